// Round 1
// baseline (447.940 us; speedup 1.0000x reference)
//
#include <hip/hip_runtime.h>
#include <hip/hip_bf16.h>

using u16 = unsigned short;
typedef __bf16 bf16x8 __attribute__((ext_vector_type(8)));
typedef float f32x4 __attribute__((ext_vector_type(4)));

// ---------- constants ----------
// B=4, S=512, KV=4096, D=1024, H=16, HD=64
#define SB 4
#define SS 512
#define SKV 4096
#define SD 1024
#define SH 16
#define SHD 64

__device__ inline u16 f2bf(float f){
  __hip_bfloat16 h = __float2bfloat16(f);
  return __builtin_bit_cast(u16, h);
}

__device__ inline bf16x8 ld_frag_g(const u16* p){
  uint4 v = *reinterpret_cast<const uint4*>(p);
  return __builtin_bit_cast(bf16x8, v);
}

// ---------- f32 -> bf16 cast ----------
__global__ __launch_bounds__(256) void cast_kernel(const float* __restrict__ src,
                                                   u16* __restrict__ dst, int n4){
  int i = blockIdx.x * 256 + threadIdx.x;
  if (i < n4){
    float4 f = reinterpret_cast<const float4*>(src)[i];
    ushort4 u;
    u.x = f2bf(f.x); u.y = f2bf(f.y); u.z = f2bf(f.z); u.w = f2bf(f.w);
    reinterpret_cast<ushort4*>(dst)[i] = u;
  }
}

// ---------- GEMM: C[M,N] = A[M,K] * W[N,K]^T (+bias), K=N=1024 ----------
enum { MODE_Q = 0, MODE_K = 1, MODE_V = 2, MODE_OUT = 3 };

template<int MODE>
__global__ __launch_bounds__(256) void gemm_bt(const u16* __restrict__ A,
                                               const u16* __restrict__ W,
                                               const float* __restrict__ bias,
                                               float* __restrict__ outF,
                                               u16* __restrict__ outB)
{
  __shared__ u16 As[128*64];
  __shared__ u16 Bs[128*64];
  const int tid  = threadIdx.x;
  const int lane = tid & 63;
  const int wm   = ((tid >> 6) >> 1) * 64;   // wave row offset
  const int wn   = ((tid >> 6) & 1) * 64;    // wave col offset
  const long rowBase = (long)blockIdx.x * 128;
  const long colBase = (long)blockIdx.y * 128;

  f32x4 acc[4][4];
#pragma unroll
  for (int i = 0; i < 4; i++)
#pragma unroll
    for (int j = 0; j < 4; j++)
      acc[i][j] = (f32x4){0.f, 0.f, 0.f, 0.f};

  for (int kt = 0; kt < 16; ++kt){          // K=1024, BK=64
    __syncthreads();
#pragma unroll
    for (int i = 0; i < 4; i++){
      int u = tid + i * 256;                // 0..1023 : 128 rows x 8 chunks(16B)
      int r = u >> 3, c = u & 7;
      uint4 va = *reinterpret_cast<const uint4*>(A + (rowBase + r) * 1024 + kt * 64 + c * 8);
      uint4 vw = *reinterpret_cast<const uint4*>(W + (colBase + r) * 1024 + kt * 64 + c * 8);
      int ob = (r * 128 + c * 16) ^ ((r & 7) << 4);   // XOR swizzle (G4)
      *reinterpret_cast<uint4*>(reinterpret_cast<char*>(As) + ob) = va;
      *reinterpret_cast<uint4*>(reinterpret_cast<char*>(Bs) + ob) = vw;
    }
    __syncthreads();
#pragma unroll
    for (int kk = 0; kk < 2; kk++){
      bf16x8 af[4], bf[4];
#pragma unroll
      for (int mi = 0; mi < 4; mi++){
        int row = wm + mi * 16 + (lane & 15);
        int ob = (row * 128 + kk * 64 + (lane >> 4) * 16) ^ ((row & 7) << 4);
        af[mi] = __builtin_bit_cast(bf16x8,
                 *reinterpret_cast<const uint4*>(reinterpret_cast<const char*>(As) + ob));
      }
#pragma unroll
      for (int ni = 0; ni < 4; ni++){
        int row = wn + ni * 16 + (lane & 15);
        int ob = (row * 128 + kk * 64 + (lane >> 4) * 16) ^ ((row & 7) << 4);
        bf[ni] = __builtin_bit_cast(bf16x8,
                 *reinterpret_cast<const uint4*>(reinterpret_cast<const char*>(Bs) + ob));
      }
#pragma unroll
      for (int mi = 0; mi < 4; mi++)
#pragma unroll
        for (int ni = 0; ni < 4; ni++)
          acc[mi][ni] = __builtin_amdgcn_mfma_f32_16x16x32_bf16(af[mi], bf[ni], acc[mi][ni], 0, 0, 0);
    }
  }

  // epilogue: D row=(lane>>4)*4+r, col=lane&15 (m89-verified layout)
#pragma unroll
  for (int mi = 0; mi < 4; mi++){
#pragma unroll
    for (int ni = 0; ni < 4; ni++){
      long gn = colBase + wn + ni * 16 + (lane & 15);
      float bb = 0.f;
      if (MODE == MODE_Q || MODE == MODE_V || MODE == MODE_OUT) bb = bias[gn];
#pragma unroll
      for (int r = 0; r < 4; r++){
        long gm = rowBase + wm + mi * 16 + ((lane >> 4) << 2) + r;
        float val = acc[mi][ni][r] + bb;
        if (MODE == MODE_OUT){
          outF[gm * 1024 + gn] = val;
        } else if (MODE == MODE_Q){
          long b = gm >> 9, s = gm & 511;
          long h = gn >> 6, hd = gn & 63;
          outB[((b * SH + h) * SS + s) * SHD + hd] = f2bf(val);
        } else { // K / V : [B,H,KV,HD]
          long b = gm >> 12, kv = gm & 4095;
          long h = gn >> 6, hd = gn & 63;
          long idx = ((b * SH + h) * SKV + kv) * SHD + hd;
          outF[idx] = val;
          outB[idx] = f2bf(val);
        }
      }
    }
  }
}

// ---------- v [B,H,KV,HD] -> vT [B,H,HD,KV] ----------
__global__ __launch_bounds__(256) void transpose_v(const u16* __restrict__ vb,
                                                   u16* __restrict__ vTb){
  __shared__ u16 t[64][72];                 // pad 8 keeps 16B row alignment (144B)
  const int tid = threadIdx.x;
  const long bh = blockIdx.y;
  const long kt = blockIdx.x;
  const u16* src = vb + (bh * SKV + kt * 64) * SHD;
#pragma unroll
  for (int i = 0; i < 2; i++){
    int u = tid + i * 256;
    int kv = u >> 3, c = u & 7;
    uint4 v = *reinterpret_cast<const uint4*>(src + kv * 64 + c * 8);
    *reinterpret_cast<uint4*>(&t[kv][c * 8]) = v;
  }
  __syncthreads();
#pragma unroll
  for (int i = 0; i < 2; i++){
    int u = tid + i * 256;
    int hd = u >> 3, ks = u & 7;
    u16 tmp[8];
#pragma unroll
    for (int j = 0; j < 8; j++) tmp[j] = t[ks * 8 + j][hd];
    *reinterpret_cast<uint4*>(vTb + (bh * SHD + hd) * SKV + kt * 64 + ks * 8) =
        *reinterpret_cast<const uint4*>(tmp);
  }
}

// ---------- flash attention: per (b*h, qtile64) ----------
__global__ __launch_bounds__(256) void attn_kernel(const u16* __restrict__ qb,
                                                   const u16* __restrict__ kb,
                                                   const u16* __restrict__ vTb,
                                                   u16* __restrict__ attn_buf){
  __shared__ u16 Plds[4][1024];             // per-wave 16x64 bf16 P tile
  const int tid  = threadIdx.x;
  const int lane = tid & 63;
  const int wid  = tid >> 6;
  const long bh  = blockIdx.x;
  const int  qt  = blockIdx.y;
  const long b = bh >> 4, h = bh & 15;

  const u16* qp = qb + (bh * SS + qt * 64 + wid * 16 + (lane & 15)) * SHD + (lane >> 4) * 8;
  const bf16x8 aq0 = ld_frag_g(qp);
  const bf16x8 aq1 = ld_frag_g(qp + 32);

  f32x4 acc[4];
#pragma unroll
  for (int i = 0; i < 4; i++) acc[i] = (f32x4){0.f, 0.f, 0.f, 0.f};
  float mrun[4], lrun[4];
#pragma unroll
  for (int r = 0; r < 4; r++){ mrun[r] = -INFINITY; lrun[r] = 0.f; }

  const u16* kbase = kb  + bh * SKV * SHD;
  const u16* vbase = vTb + bh * SHD * SKV;
  char* pbase = reinterpret_cast<char*>(&Plds[wid][0]);
  const int row0 = (lane >> 4) << 2;

  for (int kt = 0; kt < SKV / 64; ++kt){
    // scores: S[16 q][64 kv] via mfma(Q, K^T)
    f32x4 s[4];
#pragma unroll
    for (int ni = 0; ni < 4; ni++){
      const u16* kp = kbase + (kt * 64 + ni * 16 + (lane & 15)) * SHD + (lane >> 4) * 8;
      f32x4 z = (f32x4){0.f, 0.f, 0.f, 0.f};
      s[ni] = __builtin_amdgcn_mfma_f32_16x16x32_bf16(aq0, ld_frag_g(kp), z, 0, 0, 0);
      s[ni] = __builtin_amdgcn_mfma_f32_16x16x32_bf16(aq1, ld_frag_g(kp + 32), s[ni], 0, 0, 0);
      s[ni] *= 0.125f;                      // 1/sqrt(64)
    }
    // online softmax, rows live at (lane>>4)*4+r, cols at lane&15
#pragma unroll
    for (int r = 0; r < 4; r++){
      float t = fmaxf(fmaxf(s[0][r], s[1][r]), fmaxf(s[2][r], s[3][r]));
#pragma unroll
      for (int m = 1; m < 16; m <<= 1) t = fmaxf(t, __shfl_xor(t, m));
      float mn = fmaxf(mrun[r], t);
      float al = __expf(mrun[r] - mn);      // first iter: exp(-inf)=0
      float ps = 0.f;
      int row = row0 + r;
#pragma unroll
      for (int ni = 0; ni < 4; ni++){
        float p = __expf(s[ni][r] - mn);
        ps += p;
        int ob = (row * 128 + (ni * 16 + (lane & 15)) * 2) ^ ((row & 7) << 4);
        *reinterpret_cast<u16*>(pbase + ob) = f2bf(p);
      }
#pragma unroll
      for (int m = 1; m < 16; m <<= 1) ps += __shfl_xor(ps, m);
      lrun[r] = lrun[r] * al + ps;
      mrun[r] = mn;
#pragma unroll
      for (int ni = 0; ni < 4; ni++) acc[ni][r] *= al;
    }
    // PV: attn[16 q][64 hd] += P[16 q][64 kv] * V[64 kv][64 hd]
#pragma unroll
    for (int kk = 0; kk < 2; kk++){
      int row = lane & 15;
      int ob = (row * 128 + kk * 64 + (lane >> 4) * 16) ^ ((row & 7) << 4);
      bf16x8 ap = __builtin_bit_cast(bf16x8, *reinterpret_cast<const uint4*>(pbase + ob));
#pragma unroll
      for (int ni = 0; ni < 4; ni++){
        const u16* vp = vbase + (ni * 16 + (lane & 15)) * SKV + kt * 64 + kk * 32 + (lane >> 4) * 8;
        acc[ni] = __builtin_amdgcn_mfma_f32_16x16x32_bf16(ap, ld_frag_g(vp), acc[ni], 0, 0, 0);
      }
    }
  }
  // epilogue: attn_buf [B,S,D] with col = h*64+hd
#pragma unroll
  for (int ni = 0; ni < 4; ni++){
    int hd = ni * 16 + (lane & 15);
#pragma unroll
    for (int r = 0; r < 4; r++){
      long srow = (long)qt * 64 + wid * 16 + row0 + r;
      float val = acc[ni][r] / lrun[r];
      attn_buf[(b * SS + srow) * SD + h * SHD + hd] = f2bf(val);
    }
  }
}

extern "C" void kernel_launch(void* const* d_in, const int* in_sizes, int n_in,
                              void* d_out, int out_size, void* d_ws, size_t ws_size,
                              hipStream_t stream)
{
  const float* x  = (const float*)d_in[0];
  const float* xa = (const float*)d_in[1];
  const float* Wq = (const float*)d_in[2];
  const float* bq = (const float*)d_in[3];
  const float* Wk = (const float*)d_in[4];
  const float* Wv = (const float*)d_in[5];
  const float* bv = (const float*)d_in[6];
  const float* Wo = (const float*)d_in[7];
  const float* bo = (const float*)d_in[8];
  // cache_k/cache_v (d_in[9],[10]) fully overwritten since kv_len==KV — unused.

  float* outO = (float*)d_out;                        // [B,S,D]
  float* outK = outO + (long)SB * SS * SD;            // [B,H,KV,HD]
  float* outV = outK + (long)SB * SH * SKV * SHD;     // [B,H,KV,HD]

  u16* ws   = (u16*)d_ws;
  u16* xb   = ws;                                     // 2048*1024
  u16* xab  = xb   + 2048L * 1024;                    // 16384*1024
  u16* Wqb  = xab  + 16384L * 1024;
  u16* Wkb  = Wqb  + 1024L * 1024;
  u16* Wvb  = Wkb  + 1024L * 1024;
  u16* Wob  = Wvb  + 1024L * 1024;
  u16* qbuf = Wob  + 1024L * 1024;                    // [B,H,S,HD]
  u16* kbuf = qbuf + 2048L * 1024;                    // [B,H,KV,HD]
  u16* vbuf = kbuf + 16777216L;                       // [B,H,KV,HD]
  u16* vTbuf= vbuf + 16777216L;                       // [B,H,HD,KV]
  u16* attnb= vTbuf+ 16777216L;                       // [B,S,D]

  auto cast_launch = [&](const float* s, u16* d, long n){
    int n4 = (int)(n / 4);
    cast_kernel<<<(n4 + 255) / 256, 256, 0, stream>>>(s, d, n4);
  };
  cast_launch(x,  xb,  2048L * 1024);
  cast_launch(xa, xab, 16384L * 1024);
  cast_launch(Wq, Wqb, 1024L * 1024);
  cast_launch(Wk, Wkb, 1024L * 1024);
  cast_launch(Wv, Wvb, 1024L * 1024);
  cast_launch(Wo, Wob, 1024L * 1024);

  gemm_bt<MODE_Q>  <<<dim3(16, 8),  256, 0, stream>>>(xb,  Wqb, bq, nullptr, qbuf);
  gemm_bt<MODE_K>  <<<dim3(128, 8), 256, 0, stream>>>(xab, Wkb, nullptr, outK, kbuf);
  gemm_bt<MODE_V>  <<<dim3(128, 8), 256, 0, stream>>>(xab, Wvb, bv, outV, vbuf);
  transpose_v      <<<dim3(64, 64), 256, 0, stream>>>(vbuf, vTbuf);
  attn_kernel      <<<dim3(64, 8),  256, 0, stream>>>(qbuf, kbuf, vTbuf, attnb);
  gemm_bt<MODE_OUT><<<dim3(16, 8),  256, 0, stream>>>(attnb, Wob, bo, outO, nullptr);
}

// Round 2
// 432.229 us; speedup vs baseline: 1.0363x; 1.0363x over previous
//
#include <hip/hip_runtime.h>
#include <hip/hip_bf16.h>

using u16 = unsigned short;
typedef __bf16 bf16x8 __attribute__((ext_vector_type(8)));
typedef float f32x4 __attribute__((ext_vector_type(4)));

// B=4, S=512, KV=4096, D=1024, H=16, HD=64
#define SB 4
#define SS 512
#define SKV 4096
#define SD 1024
#define SH 16
#define SHD 64
#define NSPLIT 4
#define NROWS 32768   // B*H*S

__device__ inline u16 f2bf(float f){
  __hip_bfloat16 h = __float2bfloat16(f);
  return __builtin_bit_cast(u16, h);
}

__device__ inline bf16x8 ld_frag_g(const u16* p){
  uint4 v = *reinterpret_cast<const uint4*>(p);
  return __builtin_bit_cast(bf16x8, v);
}

// ---------- f32 -> bf16 cast ----------
__global__ __launch_bounds__(256) void cast_kernel(const float* __restrict__ src,
                                                   u16* __restrict__ dst, int n4){
  int i = blockIdx.x * 256 + threadIdx.x;
  if (i < n4){
    float4 f = reinterpret_cast<const float4*>(src)[i];
    ushort4 u;
    u.x = f2bf(f.x); u.y = f2bf(f.y); u.z = f2bf(f.z); u.w = f2bf(f.w);
    reinterpret_cast<ushort4*>(dst)[i] = u;
  }
}

// ---------- GEMM: C[M,N] = A[M,K] * W[N,K]^T (+bias), K=N=1024 ----------
enum { MODE_Q = 0, MODE_K = 1, MODE_V = 2, MODE_OUT = 3 };

template<int MODE>
__global__ __launch_bounds__(256) void gemm_bt(const u16* __restrict__ A,
                                               const u16* __restrict__ W,
                                               const float* __restrict__ bias,
                                               float* __restrict__ outF,
                                               u16* __restrict__ outB)
{
  __shared__ u16 As[128*64];
  __shared__ u16 Bs[128*64];
  const int tid  = threadIdx.x;
  const int lane = tid & 63;
  const int wm   = ((tid >> 6) >> 1) * 64;
  const int wn   = ((tid >> 6) & 1) * 64;
  const long rowBase = (long)blockIdx.x * 128;
  const long colBase = (long)blockIdx.y * 128;

  f32x4 acc[4][4];
#pragma unroll
  for (int i = 0; i < 4; i++)
#pragma unroll
    for (int j = 0; j < 4; j++)
      acc[i][j] = (f32x4){0.f, 0.f, 0.f, 0.f};

  for (int kt = 0; kt < 16; ++kt){
    __syncthreads();
#pragma unroll
    for (int i = 0; i < 4; i++){
      int u = tid + i * 256;
      int r = u >> 3, c = u & 7;
      uint4 va = *reinterpret_cast<const uint4*>(A + (rowBase + r) * 1024 + kt * 64 + c * 8);
      uint4 vw = *reinterpret_cast<const uint4*>(W + (colBase + r) * 1024 + kt * 64 + c * 8);
      int ob = (r * 128 + c * 16) ^ ((r & 7) << 4);
      *reinterpret_cast<uint4*>(reinterpret_cast<char*>(As) + ob) = va;
      *reinterpret_cast<uint4*>(reinterpret_cast<char*>(Bs) + ob) = vw;
    }
    __syncthreads();
#pragma unroll
    for (int kk = 0; kk < 2; kk++){
      bf16x8 af[4], bfr[4];
#pragma unroll
      for (int mi = 0; mi < 4; mi++){
        int row = wm + mi * 16 + (lane & 15);
        int ob = (row * 128 + kk * 64 + (lane >> 4) * 16) ^ ((row & 7) << 4);
        af[mi] = __builtin_bit_cast(bf16x8,
                 *reinterpret_cast<const uint4*>(reinterpret_cast<const char*>(As) + ob));
      }
#pragma unroll
      for (int ni = 0; ni < 4; ni++){
        int row = wn + ni * 16 + (lane & 15);
        int ob = (row * 128 + kk * 64 + (lane >> 4) * 16) ^ ((row & 7) << 4);
        bfr[ni] = __builtin_bit_cast(bf16x8,
                 *reinterpret_cast<const uint4*>(reinterpret_cast<const char*>(Bs) + ob));
      }
#pragma unroll
      for (int mi = 0; mi < 4; mi++)
#pragma unroll
        for (int ni = 0; ni < 4; ni++)
          acc[mi][ni] = __builtin_amdgcn_mfma_f32_16x16x32_bf16(af[mi], bfr[ni], acc[mi][ni], 0, 0, 0);
    }
  }

#pragma unroll
  for (int mi = 0; mi < 4; mi++){
#pragma unroll
    for (int ni = 0; ni < 4; ni++){
      long gn = colBase + wn + ni * 16 + (lane & 15);
      float bb = 0.f;
      if (MODE == MODE_Q || MODE == MODE_V || MODE == MODE_OUT) bb = bias[gn];
#pragma unroll
      for (int r = 0; r < 4; r++){
        long gm = rowBase + wm + mi * 16 + ((lane >> 4) << 2) + r;
        float val = acc[mi][ni][r] + bb;
        if (MODE == MODE_OUT){
          outF[gm * 1024 + gn] = val;
        } else if (MODE == MODE_Q){
          long b = gm >> 9, s = gm & 511;
          long h = gn >> 6, hd = gn & 63;
          outB[((b * SH + h) * SS + s) * SHD + hd] = f2bf(val);
        } else if (MODE == MODE_K){
          long b = gm >> 12, kv = gm & 4095;
          long h = gn >> 6, hd = gn & 63;
          long idx = ((b * SH + h) * SKV + kv) * SHD + hd;
          outF[idx] = val;
          outB[idx] = f2bf(val);
        } else { // MODE_V: f32 only; bf16 transpose reads from f32
          long b = gm >> 12, kv = gm & 4095;
          long h = gn >> 6, hd = gn & 63;
          outF[((b * SH + h) * SKV + kv) * SHD + hd] = val;
        }
      }
    }
  }
}

// ---------- v f32 [B,H,KV,HD] -> vT bf16 [B,H,HD,KV] ----------
__global__ __launch_bounds__(256) void transpose_v(const float* __restrict__ vf,
                                                   u16* __restrict__ vTb){
  __shared__ u16 t[64][72];
  const int tid = threadIdx.x;
  const long bh = blockIdx.y;
  const long kt = blockIdx.x;
  const float* src = vf + (bh * SKV + kt * 64) * SHD;
#pragma unroll
  for (int i = 0; i < 4; i++){
    int u = tid + i * 256;              // float4 id in [0,1024)
    int kv = u >> 4, c = u & 15;
    float4 f = reinterpret_cast<const float4*>(src)[kv * 16 + c];
    ushort4 uu;
    uu.x = f2bf(f.x); uu.y = f2bf(f.y); uu.z = f2bf(f.z); uu.w = f2bf(f.w);
    *reinterpret_cast<ushort4*>(&t[kv][c * 4]) = uu;
  }
  __syncthreads();
#pragma unroll
  for (int i = 0; i < 2; i++){
    int u = tid + i * 256;
    int hd = u >> 3, ks = u & 7;
    u16 tmp[8];
#pragma unroll
    for (int j = 0; j < 8; j++) tmp[j] = t[ks * 8 + j][hd];
    *reinterpret_cast<uint4*>(vTb + (bh * SHD + hd) * SKV + kt * 64 + ks * 8) =
        *reinterpret_cast<const uint4*>(tmp);
  }
}

// ---------- flash attention partial: per (bh, qtile64, kv-split) ----------
__global__ __launch_bounds__(256) void attn_partial(const u16* __restrict__ qb,
                                                    const u16* __restrict__ kb,
                                                    const u16* __restrict__ vTb,
                                                    float* __restrict__ opart,
                                                    float* __restrict__ ml){
  __shared__ u16 Plds[4][1024];
  const int tid  = threadIdx.x;
  const int lane = tid & 63;
  const int wid  = tid >> 6;
  const long bh  = blockIdx.x;
  const int  qt  = blockIdx.y;
  const int  split = blockIdx.z;

  const u16* qp = qb + (bh * SS + qt * 64 + wid * 16 + (lane & 15)) * SHD + (lane >> 4) * 8;
  const bf16x8 aq0 = ld_frag_g(qp);
  const bf16x8 aq1 = ld_frag_g(qp + 32);

  f32x4 acc[4];
#pragma unroll
  for (int i = 0; i < 4; i++) acc[i] = (f32x4){0.f, 0.f, 0.f, 0.f};
  float mrun[4], lrun[4];
#pragma unroll
  for (int r = 0; r < 4; r++){ mrun[r] = -INFINITY; lrun[r] = 0.f; }

  const u16* kbase = kb  + bh * SKV * SHD;
  const u16* vbase = vTb + bh * SHD * SKV;
  char* pbase = reinterpret_cast<char*>(&Plds[wid][0]);
  const int row0 = (lane >> 4) << 2;

  for (int kt = split * 16; kt < split * 16 + 16; ++kt){
    f32x4 s[4];
#pragma unroll
    for (int ni = 0; ni < 4; ni++){
      const u16* kp = kbase + (kt * 64 + ni * 16 + (lane & 15)) * SHD + (lane >> 4) * 8;
      f32x4 z = (f32x4){0.f, 0.f, 0.f, 0.f};
      s[ni] = __builtin_amdgcn_mfma_f32_16x16x32_bf16(aq0, ld_frag_g(kp), z, 0, 0, 0);
      s[ni] = __builtin_amdgcn_mfma_f32_16x16x32_bf16(aq1, ld_frag_g(kp + 32), s[ni], 0, 0, 0);
      s[ni] *= 0.125f;
    }
#pragma unroll
    for (int r = 0; r < 4; r++){
      float t = fmaxf(fmaxf(s[0][r], s[1][r]), fmaxf(s[2][r], s[3][r]));
#pragma unroll
      for (int m = 1; m < 16; m <<= 1) t = fmaxf(t, __shfl_xor(t, m));
      float mn = fmaxf(mrun[r], t);
      float al = __expf(mrun[r] - mn);
      float ps = 0.f;
      int row = row0 + r;
#pragma unroll
      for (int ni = 0; ni < 4; ni++){
        float p = __expf(s[ni][r] - mn);
        ps += p;
        int ob = (row * 128 + (ni * 16 + (lane & 15)) * 2) ^ ((row & 7) << 4);
        *reinterpret_cast<u16*>(pbase + ob) = f2bf(p);
      }
#pragma unroll
      for (int m = 1; m < 16; m <<= 1) ps += __shfl_xor(ps, m);
      lrun[r] = lrun[r] * al + ps;
      mrun[r] = mn;
#pragma unroll
      for (int ni = 0; ni < 4; ni++) acc[ni][r] *= al;
    }
#pragma unroll
    for (int kk = 0; kk < 2; kk++){
      int row = lane & 15;
      int ob = (row * 128 + kk * 64 + (lane >> 4) * 16) ^ ((row & 7) << 4);
      bf16x8 ap = __builtin_bit_cast(bf16x8, *reinterpret_cast<const uint4*>(pbase + ob));
#pragma unroll
      for (int ni = 0; ni < 4; ni++){
        const u16* vp = vbase + (ni * 16 + (lane & 15)) * SKV + kt * 64 + kk * 32 + (lane >> 4) * 8;
        acc[ni] = __builtin_amdgcn_mfma_f32_16x16x32_bf16(ap, ld_frag_g(vp), acc[ni], 0, 0, 0);
      }
    }
  }

  // epilogue: unnormalized partials + per-row m,l
  const long rowbase = bh * SS + (long)qt * 64 + wid * 16;
#pragma unroll
  for (int ni = 0; ni < 4; ni++){
    int hd = ni * 16 + (lane & 15);
#pragma unroll
    for (int r = 0; r < 4; r++){
      long row = rowbase + row0 + r;
      opart[((long)split * NROWS + row) * SHD + hd] = acc[ni][r];
    }
  }
  if ((lane & 15) == 0){
#pragma unroll
    for (int r = 0; r < 4; r++){
      long row = rowbase + row0 + r;
      ml[(long)split * NROWS + row] = mrun[r];
      ml[(long)NSPLIT * NROWS + (long)split * NROWS + row] = lrun[r];
    }
  }
}

// ---------- combine partials -> attnb bf16 [B,S,D] ----------
__global__ __launch_bounds__(256) void attn_combine(const float* __restrict__ opart,
                                                    const float* __restrict__ ml,
                                                    u16* __restrict__ attnb){
  long idx4 = (long)blockIdx.x * 256 + threadIdx.x;   // float4 id, 16 per row
  long row = idx4 >> 4;
  int  c   = (int)(idx4 & 15);
  float m0 = ml[row], m1 = ml[NROWS + row], m2 = ml[2L*NROWS + row], m3 = ml[3L*NROWS + row];
  float M = fmaxf(fmaxf(m0, m1), fmaxf(m2, m3));
  float w0 = __expf(m0 - M), w1 = __expf(m1 - M), w2 = __expf(m2 - M), w3 = __expf(m3 - M);
  const float* lb = ml + (long)NSPLIT * NROWS;
  float L = w0*lb[row] + w1*lb[NROWS+row] + w2*lb[2L*NROWS+row] + w3*lb[3L*NROWS+row];
  float inv = 1.f / L;
  const float4* op = reinterpret_cast<const float4*>(opart);
  float4 v0 = op[(0L*NROWS + row) * 16 + c];
  float4 v1 = op[(1L*NROWS + row) * 16 + c];
  float4 v2 = op[(2L*NROWS + row) * 16 + c];
  float4 v3 = op[(3L*NROWS + row) * 16 + c];
  float4 val;
  val.x = (w0*v0.x + w1*v1.x + w2*v2.x + w3*v3.x) * inv;
  val.y = (w0*v0.y + w1*v1.y + w2*v2.y + w3*v3.y) * inv;
  val.z = (w0*v0.z + w1*v1.z + w2*v2.z + w3*v3.z) * inv;
  val.w = (w0*v0.w + w1*v1.w + w2*v2.w + w3*v3.w) * inv;
  long bh = row >> 9, s = row & 511;
  long b = bh >> 4, h = bh & 15;
  ushort4 u;
  u.x = f2bf(val.x); u.y = f2bf(val.y); u.z = f2bf(val.z); u.w = f2bf(val.w);
  reinterpret_cast<ushort4*>(attnb)[((b * SS + s) * SD + h * SHD) / 4 + c] = u;
}

extern "C" void kernel_launch(void* const* d_in, const int* in_sizes, int n_in,
                              void* d_out, int out_size, void* d_ws, size_t ws_size,
                              hipStream_t stream)
{
  const float* x  = (const float*)d_in[0];
  const float* xa = (const float*)d_in[1];
  const float* Wq = (const float*)d_in[2];
  const float* bq = (const float*)d_in[3];
  const float* Wk = (const float*)d_in[4];
  const float* Wv = (const float*)d_in[5];
  const float* bv = (const float*)d_in[6];
  const float* Wo = (const float*)d_in[7];
  const float* bo = (const float*)d_in[8];

  float* outO = (float*)d_out;
  float* outK = outO + (long)SB * SS * SD;
  float* outV = outK + (long)SB * SH * SKV * SHD;

  u16* ws   = (u16*)d_ws;
  u16* xb   = ws;                                     // 2M u16 (reused as attnb)
  u16* xab  = xb   + 2097152L;                        // 16.7M u16 (reused as opart f32)
  u16* Wqb  = xab  + 16777216L;
  u16* Wkb  = Wqb  + 1048576L;
  u16* Wvb  = Wkb  + 1048576L;
  u16* Wob  = Wvb  + 1048576L;
  u16* qbuf = Wob  + 1048576L;                        // [B,H,S,HD] bf16
  u16* kbuf = qbuf + 2097152L;                        // [B,H,KV,HD] bf16
  u16* vTbuf= kbuf + 16777216L;                       // [B,H,HD,KV] bf16
  u16* mlb  = vTbuf+ 16777216L;                       // 8*32768 f32 = 524288 u16

  u16*   attnb = xb;                                  // alias: xb dead after gemm_Q
  float* opart = (float*)xab;                         // alias: xab dead after gemm_V
  float* ml    = (float*)mlb;

  auto cast_launch = [&](const float* s, u16* d, long n){
    int n4 = (int)(n / 4);
    cast_kernel<<<(n4 + 255) / 256, 256, 0, stream>>>(s, d, n4);
  };
  cast_launch(x,  xb,  2097152L);
  cast_launch(xa, xab, 16777216L);
  cast_launch(Wq, Wqb, 1048576L);
  cast_launch(Wk, Wkb, 1048576L);
  cast_launch(Wv, Wvb, 1048576L);
  cast_launch(Wo, Wob, 1048576L);

  gemm_bt<MODE_Q>  <<<dim3(16, 8),  256, 0, stream>>>(xb,  Wqb, bq, nullptr, qbuf);
  gemm_bt<MODE_K>  <<<dim3(128, 8), 256, 0, stream>>>(xab, Wkb, nullptr, outK, kbuf);
  gemm_bt<MODE_V>  <<<dim3(128, 8), 256, 0, stream>>>(xab, Wvb, bv, outV, nullptr);
  transpose_v      <<<dim3(64, 64), 256, 0, stream>>>(outV, vTbuf);
  attn_partial     <<<dim3(64, 8, NSPLIT), 256, 0, stream>>>(qbuf, kbuf, vTbuf, opart, ml);
  attn_combine     <<<2048, 256, 0, stream>>>(opart, ml, attnb);
  gemm_bt<MODE_OUT><<<dim3(16, 8),  256, 0, stream>>>(attnb, Wob, bo, outO, nullptr);
}

// Round 3
// 427.035 us; speedup vs baseline: 1.0490x; 1.0122x over previous
//
#include <hip/hip_runtime.h>
#include <hip/hip_bf16.h>

using u16 = unsigned short;
typedef __bf16 bf16x8 __attribute__((ext_vector_type(8)));
typedef float f32x4 __attribute__((ext_vector_type(4)));

// B=4, S=512, KV=4096, D=1024, H=16, HD=64
#define SB 4
#define SS 512
#define SKV 4096
#define SD 1024
#define SH 16
#define SHD 64
#define NSPLIT 4
#define NROWS 32768   // B*H*S

__device__ inline u16 f2bf(float f){
  __hip_bfloat16 h = __float2bfloat16(f);
  return __builtin_bit_cast(u16, h);
}

__device__ inline bf16x8 ld_frag_g(const u16* p){
  uint4 v = *reinterpret_cast<const uint4*>(p);
  return __builtin_bit_cast(bf16x8, v);
}

// ---------- f32 -> bf16 cast ----------
__global__ __launch_bounds__(256) void cast_kernel(const float* __restrict__ src,
                                                   u16* __restrict__ dst, int n4){
  int i = blockIdx.x * 256 + threadIdx.x;
  if (i < n4){
    float4 f = reinterpret_cast<const float4*>(src)[i];
    ushort4 u;
    u.x = f2bf(f.x); u.y = f2bf(f.y); u.z = f2bf(f.z); u.w = f2bf(f.w);
    reinterpret_cast<ushort4*>(dst)[i] = u;
  }
}

// ---------- GEMM: C[M,N] = A[M,K] * W[N,K]^T (+bias), K=N=1024 ----------
enum { MODE_Q = 0, MODE_K = 1, MODE_V = 2, MODE_OUT = 3 };

template<int MODE>
__global__ __launch_bounds__(256) void gemm_bt(const u16* __restrict__ A,
                                               const u16* __restrict__ W,
                                               const float* __restrict__ bias,
                                               float* __restrict__ outF,
                                               u16* __restrict__ outB)
{
  __shared__ u16 As[128*64];
  __shared__ u16 Bs[128*64];
  const int tid  = threadIdx.x;
  const int lane = tid & 63;
  const int wm   = ((tid >> 6) >> 1) * 64;
  const int wn   = ((tid >> 6) & 1) * 64;
  const long rowBase = (long)blockIdx.x * 128;
  const long colBase = (long)blockIdx.y * 128;

  f32x4 acc[4][4];
#pragma unroll
  for (int i = 0; i < 4; i++)
#pragma unroll
    for (int j = 0; j < 4; j++)
      acc[i][j] = (f32x4){0.f, 0.f, 0.f, 0.f};

  for (int kt = 0; kt < 16; ++kt){
    __syncthreads();
#pragma unroll
    for (int i = 0; i < 4; i++){
      int u = tid + i * 256;
      int r = u >> 3, c = u & 7;
      uint4 va = *reinterpret_cast<const uint4*>(A + (rowBase + r) * 1024 + kt * 64 + c * 8);
      uint4 vw = *reinterpret_cast<const uint4*>(W + (colBase + r) * 1024 + kt * 64 + c * 8);
      int ob = (r * 128 + c * 16) ^ ((r & 7) << 4);
      *reinterpret_cast<uint4*>(reinterpret_cast<char*>(As) + ob) = va;
      *reinterpret_cast<uint4*>(reinterpret_cast<char*>(Bs) + ob) = vw;
    }
    __syncthreads();
#pragma unroll
    for (int kk = 0; kk < 2; kk++){
      bf16x8 af[4], bfr[4];
#pragma unroll
      for (int mi = 0; mi < 4; mi++){
        int row = wm + mi * 16 + (lane & 15);
        int ob = (row * 128 + kk * 64 + (lane >> 4) * 16) ^ ((row & 7) << 4);
        af[mi] = __builtin_bit_cast(bf16x8,
                 *reinterpret_cast<const uint4*>(reinterpret_cast<const char*>(As) + ob));
      }
#pragma unroll
      for (int ni = 0; ni < 4; ni++){
        int row = wn + ni * 16 + (lane & 15);
        int ob = (row * 128 + kk * 64 + (lane >> 4) * 16) ^ ((row & 7) << 4);
        bfr[ni] = __builtin_bit_cast(bf16x8,
                 *reinterpret_cast<const uint4*>(reinterpret_cast<const char*>(Bs) + ob));
      }
#pragma unroll
      for (int mi = 0; mi < 4; mi++)
#pragma unroll
        for (int ni = 0; ni < 4; ni++)
          acc[mi][ni] = __builtin_amdgcn_mfma_f32_16x16x32_bf16(af[mi], bfr[ni], acc[mi][ni], 0, 0, 0);
    }
  }

#pragma unroll
  for (int mi = 0; mi < 4; mi++){
#pragma unroll
    for (int ni = 0; ni < 4; ni++){
      long gn = colBase + wn + ni * 16 + (lane & 15);
      float bb = 0.f;
      if (MODE == MODE_Q || MODE == MODE_V || MODE == MODE_OUT) bb = bias[gn];
      if (MODE == MODE_V){
        // f32 updated_v + fused bf16 transpose (vT[b,h,hd,kv])
        long gmBase = rowBase + wm + mi * 16 + ((lane >> 4) << 2);
        long b = gmBase >> 12, kv = gmBase & 4095;
        long h = gn >> 6, hd = gn & 63;
        long fidx = ((b * SH + h) * SKV + kv) * SHD + hd;
        ushort4 pk;
        float v0 = acc[mi][ni][0] + bb; outF[fidx          ] = v0; pk.x = f2bf(v0);
        float v1 = acc[mi][ni][1] + bb; outF[fidx +     SHD] = v1; pk.y = f2bf(v1);
        float v2 = acc[mi][ni][2] + bb; outF[fidx + 2 * SHD] = v2; pk.z = f2bf(v2);
        float v3 = acc[mi][ni][3] + bb; outF[fidx + 3 * SHD] = v3; pk.w = f2bf(v3);
        *reinterpret_cast<ushort4*>(outB + ((b * SH + h) * SHD + hd) * SKV + kv) = pk;
      } else {
#pragma unroll
        for (int r = 0; r < 4; r++){
          long gm = rowBase + wm + mi * 16 + ((lane >> 4) << 2) + r;
          float val = acc[mi][ni][r] + bb;
          if (MODE == MODE_OUT){
            outF[gm * 1024 + gn] = val;
          } else if (MODE == MODE_Q){
            long b = gm >> 9, s = gm & 511;
            long h = gn >> 6, hd = gn & 63;
            outB[((b * SH + h) * SS + s) * SHD + hd] = f2bf(val);
          } else { // MODE_K
            long b = gm >> 12, kv = gm & 4095;
            long h = gn >> 6, hd = gn & 63;
            long idx = ((b * SH + h) * SKV + kv) * SHD + hd;
            outF[idx] = val;
            outB[idx] = f2bf(val);
          }
        }
      }
    }
  }
}

// ---------- flash attention partial, swapped-operand QK^T/PV ----------
// Per wave: 16 q rows. Lane c=lane&15 owns q-row c; hi=lane>>4.
// S^T[kv][q]: sT[ni][r] = S[kv=16ni+4hi+r][q=c]  -> softmax per-lane scalar m/l
// O^T[hd][q]: acc[ni][r] = O[hd=16ni+4hi+r][q=c]
__global__ __launch_bounds__(256) void attn_partial(const u16* __restrict__ qb,
                                                    const u16* __restrict__ kb,
                                                    const u16* __restrict__ vTb,
                                                    float* __restrict__ opart,
                                                    float* __restrict__ ml){
  __shared__ u16 PT[4][16 * 72];            // per-wave P^T[q][kv], row stride 72 u16
  const int tid  = threadIdx.x;
  const int lane = tid & 63;
  const int wid  = tid >> 6;
  const int c    = lane & 15;
  const int hi   = lane >> 4;
  const long bh  = blockIdx.x;
  const int  qt  = blockIdx.y;
  const int  split = blockIdx.z;

  // Q as B-fragment: lane holds Q[q=c][hd = hi*8 .. +8] (+32 for k-half 1)
  const u16* qp = qb + (bh * SS + qt * 64 + wid * 16 + c) * SHD + hi * 8;
  const bf16x8 bq0 = ld_frag_g(qp);
  const bf16x8 bq1 = ld_frag_g(qp + 32);

  f32x4 acc[4];
#pragma unroll
  for (int i = 0; i < 4; i++) acc[i] = (f32x4){0.f, 0.f, 0.f, 0.f};
  float mrun = -INFINITY, lrun = 0.f;

  const u16* kbase = kb  + bh * SKV * SHD;
  const u16* vbase = vTb + bh * SHD * SKV;
  u16* pt = &PT[wid][0];

  for (int kt = split * 16; kt < split * 16 + 16; ++kt){
    // S^T = K · Q^T : 8 MFMAs
    f32x4 sT[4];
#pragma unroll
    for (int ni = 0; ni < 4; ni++){
      const u16* kp = kbase + (kt * 64 + ni * 16 + c) * SHD + hi * 8;
      f32x4 z = (f32x4){0.f, 0.f, 0.f, 0.f};
      sT[ni] = __builtin_amdgcn_mfma_f32_16x16x32_bf16(ld_frag_g(kp), bq0, z, 0, 0, 0);
      sT[ni] = __builtin_amdgcn_mfma_f32_16x16x32_bf16(ld_frag_g(kp + 32), bq1, sT[ni], 0, 0, 0);
      sT[ni] *= 0.125f;                     // 1/sqrt(64)
    }
    // per-lane softmax for q-row c: local 16-reg reduce + 2 shuffles
    f32x4 mv = __builtin_elementwise_max(__builtin_elementwise_max(sT[0], sT[1]),
                                         __builtin_elementwise_max(sT[2], sT[3]));
    float t = fmaxf(fmaxf(mv[0], mv[1]), fmaxf(mv[2], mv[3]));
    t = fmaxf(t, __shfl_xor(t, 16));
    t = fmaxf(t, __shfl_xor(t, 32));
    float mn = fmaxf(mrun, t);
    float al = __expf(mrun - mn);
    f32x4 psv = (f32x4){0.f, 0.f, 0.f, 0.f};
#pragma unroll
    for (int ni = 0; ni < 4; ni++){
      f32x4 p;
      p[0] = __expf(sT[ni][0] - mn); p[1] = __expf(sT[ni][1] - mn);
      p[2] = __expf(sT[ni][2] - mn); p[3] = __expf(sT[ni][3] - mn);
      psv += p;
      ushort4 pk;
      pk.x = f2bf(p[0]); pk.y = f2bf(p[1]); pk.z = f2bf(p[2]); pk.w = f2bf(p[3]);
      // P^T[q=c][kv = 16ni + 4hi + 0..3]
      *reinterpret_cast<ushort4*>(pt + c * 72 + ni * 16 + hi * 4) = pk;
    }
    float ps = (psv[0] + psv[1]) + (psv[2] + psv[3]);
    ps += __shfl_xor(ps, 16);
    ps += __shfl_xor(ps, 32);
    lrun = lrun * al + ps;
    mrun = mn;
#pragma unroll
    for (int ni = 0; ni < 4; ni++) acc[ni] *= al;
    // O^T += V^T · P^T : 8 MFMAs
#pragma unroll
    for (int m = 0; m < 2; m++){
      bf16x8 pfrag = __builtin_bit_cast(bf16x8,
          *reinterpret_cast<const uint4*>(pt + c * 72 + m * 32 + hi * 8));
#pragma unroll
      for (int ni = 0; ni < 4; ni++){
        const u16* vp = vbase + (ni * 16 + c) * SKV + kt * 64 + m * 32 + hi * 8;
        acc[ni] = __builtin_amdgcn_mfma_f32_16x16x32_bf16(ld_frag_g(vp), pfrag, acc[ni], 0, 0, 0);
      }
    }
  }

  // epilogue: unnormalized O^T partials + per-row m,l
  const long row = bh * SS + (long)qt * 64 + wid * 16 + c;
  float* ob = opart + ((long)split * NROWS + row) * SHD;
#pragma unroll
  for (int ni = 0; ni < 4; ni++)
    *reinterpret_cast<f32x4*>(ob + ni * 16 + hi * 4) = acc[ni];
  if (hi == 0){
    ml[(long)split * NROWS + row] = mrun;
    ml[(long)NSPLIT * NROWS + (long)split * NROWS + row] = lrun;
  }
}

// ---------- combine partials -> attnb bf16 [B,S,D] ----------
__global__ __launch_bounds__(256) void attn_combine(const float* __restrict__ opart,
                                                    const float* __restrict__ ml,
                                                    u16* __restrict__ attnb){
  long idx4 = (long)blockIdx.x * 256 + threadIdx.x;   // float4 id, 16 per row
  long row = idx4 >> 4;
  int  c   = (int)(idx4 & 15);
  float m0 = ml[row], m1 = ml[NROWS + row], m2 = ml[2L*NROWS + row], m3 = ml[3L*NROWS + row];
  float M = fmaxf(fmaxf(m0, m1), fmaxf(m2, m3));
  float w0 = __expf(m0 - M), w1 = __expf(m1 - M), w2 = __expf(m2 - M), w3 = __expf(m3 - M);
  const float* lb = ml + (long)NSPLIT * NROWS;
  float L = w0*lb[row] + w1*lb[NROWS+row] + w2*lb[2L*NROWS+row] + w3*lb[3L*NROWS+row];
  float inv = 1.f / L;
  const float4* op = reinterpret_cast<const float4*>(opart);
  float4 v0 = op[(0L*NROWS + row) * 16 + c];
  float4 v1 = op[(1L*NROWS + row) * 16 + c];
  float4 v2 = op[(2L*NROWS + row) * 16 + c];
  float4 v3 = op[(3L*NROWS + row) * 16 + c];
  float4 val;
  val.x = (w0*v0.x + w1*v1.x + w2*v2.x + w3*v3.x) * inv;
  val.y = (w0*v0.y + w1*v1.y + w2*v2.y + w3*v3.y) * inv;
  val.z = (w0*v0.z + w1*v1.z + w2*v2.z + w3*v3.z) * inv;
  val.w = (w0*v0.w + w1*v1.w + w2*v2.w + w3*v3.w) * inv;
  long bh = row >> 9, s = row & 511;
  long b = bh >> 4, h = bh & 15;
  ushort4 u;
  u.x = f2bf(val.x); u.y = f2bf(val.y); u.z = f2bf(val.z); u.w = f2bf(val.w);
  reinterpret_cast<ushort4*>(attnb)[((b * SS + s) * SD + h * SHD) / 4 + c] = u;
}

extern "C" void kernel_launch(void* const* d_in, const int* in_sizes, int n_in,
                              void* d_out, int out_size, void* d_ws, size_t ws_size,
                              hipStream_t stream)
{
  const float* x  = (const float*)d_in[0];
  const float* xa = (const float*)d_in[1];
  const float* Wq = (const float*)d_in[2];
  const float* bq = (const float*)d_in[3];
  const float* Wk = (const float*)d_in[4];
  const float* Wv = (const float*)d_in[5];
  const float* bv = (const float*)d_in[6];
  const float* Wo = (const float*)d_in[7];
  const float* bo = (const float*)d_in[8];

  float* outO = (float*)d_out;
  float* outK = outO + (long)SB * SS * SD;
  float* outV = outK + (long)SB * SH * SKV * SHD;

  u16* ws   = (u16*)d_ws;
  u16* xb   = ws;                                     // 2M u16 (reused as attnb)
  u16* xab  = xb   + 2097152L;                        // 16.7M u16 (reused as opart f32)
  u16* Wqb  = xab  + 16777216L;
  u16* Wkb  = Wqb  + 1048576L;
  u16* Wvb  = Wkb  + 1048576L;
  u16* Wob  = Wvb  + 1048576L;
  u16* qbuf = Wob  + 1048576L;                        // [B,H,S,HD] bf16
  u16* kbuf = qbuf + 2097152L;                        // [B,H,KV,HD] bf16
  u16* vTbuf= kbuf + 16777216L;                       // [B,H,HD,KV] bf16
  u16* mlb  = vTbuf+ 16777216L;                       // 8*32768 f32

  u16*   attnb = xb;                                  // alias: xb dead after gemm_Q
  float* opart = (float*)xab;                         // alias: xab dead after gemm_V
  float* ml    = (float*)mlb;

  auto cast_launch = [&](const float* s, u16* d, long n){
    int n4 = (int)(n / 4);
    cast_kernel<<<(n4 + 255) / 256, 256, 0, stream>>>(s, d, n4);
  };
  cast_launch(x,  xb,  2097152L);
  cast_launch(xa, xab, 16777216L);
  cast_launch(Wq, Wqb, 1048576L);
  cast_launch(Wk, Wkb, 1048576L);
  cast_launch(Wv, Wvb, 1048576L);
  cast_launch(Wo, Wob, 1048576L);

  gemm_bt<MODE_Q>  <<<dim3(16, 8),  256, 0, stream>>>(xb,  Wqb, bq, nullptr, qbuf);
  gemm_bt<MODE_K>  <<<dim3(128, 8), 256, 0, stream>>>(xab, Wkb, nullptr, outK, kbuf);
  gemm_bt<MODE_V>  <<<dim3(128, 8), 256, 0, stream>>>(xab, Wvb, bv, outV, vTbuf);
  attn_partial     <<<dim3(64, 8, NSPLIT), 256, 0, stream>>>(qbuf, kbuf, vTbuf, opart, ml);
  attn_combine     <<<2048, 256, 0, stream>>>(opart, ml, attnb);
  gemm_bt<MODE_OUT><<<dim3(16, 8),  256, 0, stream>>>(attnb, Wob, bo, outO, nullptr);
}

// Round 4
// 275.047 us; speedup vs baseline: 1.6286x; 1.5526x over previous
//
#include <hip/hip_runtime.h>
#include <hip/hip_bf16.h>

using u16 = unsigned short;
typedef __bf16 bf16x8 __attribute__((ext_vector_type(8)));
typedef float f32x4 __attribute__((ext_vector_type(4)));

// B=4, S=512, KV=4096, D=1024, H=16, HD=64
#define SB 4
#define SS 512
#define SKV 4096
#define SD 1024
#define SH 16
#define SHD 64
#define NSPLIT 4
#define NROWS 32768   // B*H*S

__device__ inline u16 f2bf(float f){
  __hip_bfloat16 h = __float2bfloat16(f);
  return __builtin_bit_cast(u16, h);
}

__device__ inline bf16x8 ld_frag_g(const u16* p){
  uint4 v = *reinterpret_cast<const uint4*>(p);
  return __builtin_bit_cast(bf16x8, v);
}

__device__ inline bf16x8 ld_frag_lds(const char* base, int ob){
  uint4 v = *reinterpret_cast<const uint4*>(base + ob);
  return __builtin_bit_cast(bf16x8, v);
}

// ---------- f32 -> bf16 cast ----------
__global__ __launch_bounds__(256) void cast_kernel(const float* __restrict__ src,
                                                   u16* __restrict__ dst, int n4){
  int i = blockIdx.x * 256 + threadIdx.x;
  if (i < n4){
    float4 f = reinterpret_cast<const float4*>(src)[i];
    ushort4 u;
    u.x = f2bf(f.x); u.y = f2bf(f.y); u.z = f2bf(f.z); u.w = f2bf(f.w);
    reinterpret_cast<ushort4*>(dst)[i] = u;
  }
}

// ---------- GEMM: C[M,N] = A[M,K] * W[N,K]^T (+bias), K=N=1024 ----------
enum { MODE_Q = 0, MODE_K = 1, MODE_V = 2, MODE_OUT = 3 };

template<int MODE>
__global__ __launch_bounds__(256) void gemm_bt(const u16* __restrict__ A,
                                               const u16* __restrict__ W,
                                               const float* __restrict__ bias,
                                               float* __restrict__ outF,
                                               u16* __restrict__ outB)
{
  __shared__ u16 As[128*64];
  __shared__ u16 Bs[128*64];
  const int tid  = threadIdx.x;
  const int lane = tid & 63;
  const int wm   = ((tid >> 6) >> 1) * 64;
  const int wn   = ((tid >> 6) & 1) * 64;
  const long rowBase = (long)blockIdx.x * 128;
  const long colBase = (long)blockIdx.y * 128;

  f32x4 acc[4][4];
#pragma unroll
  for (int i = 0; i < 4; i++)
#pragma unroll
    for (int j = 0; j < 4; j++)
      acc[i][j] = (f32x4){0.f, 0.f, 0.f, 0.f};

  for (int kt = 0; kt < 16; ++kt){
    __syncthreads();
#pragma unroll
    for (int i = 0; i < 4; i++){
      int u = tid + i * 256;
      int r = u >> 3, c = u & 7;
      uint4 va = *reinterpret_cast<const uint4*>(A + (rowBase + r) * 1024 + kt * 64 + c * 8);
      uint4 vw = *reinterpret_cast<const uint4*>(W + (colBase + r) * 1024 + kt * 64 + c * 8);
      int ob = (r * 128 + c * 16) ^ ((r & 7) << 4);
      *reinterpret_cast<uint4*>(reinterpret_cast<char*>(As) + ob) = va;
      *reinterpret_cast<uint4*>(reinterpret_cast<char*>(Bs) + ob) = vw;
    }
    __syncthreads();
#pragma unroll
    for (int kk = 0; kk < 2; kk++){
      bf16x8 af[4], bfr[4];
#pragma unroll
      for (int mi = 0; mi < 4; mi++){
        int row = wm + mi * 16 + (lane & 15);
        int ob = (row * 128 + kk * 64 + (lane >> 4) * 16) ^ ((row & 7) << 4);
        af[mi] = __builtin_bit_cast(bf16x8,
                 *reinterpret_cast<const uint4*>(reinterpret_cast<const char*>(As) + ob));
      }
#pragma unroll
      for (int ni = 0; ni < 4; ni++){
        int row = wn + ni * 16 + (lane & 15);
        int ob = (row * 128 + kk * 64 + (lane >> 4) * 16) ^ ((row & 7) << 4);
        bfr[ni] = __builtin_bit_cast(bf16x8,
                 *reinterpret_cast<const uint4*>(reinterpret_cast<const char*>(Bs) + ob));
      }
#pragma unroll
      for (int mi = 0; mi < 4; mi++)
#pragma unroll
        for (int ni = 0; ni < 4; ni++)
          acc[mi][ni] = __builtin_amdgcn_mfma_f32_16x16x32_bf16(af[mi], bfr[ni], acc[mi][ni], 0, 0, 0);
    }
  }

#pragma unroll
  for (int mi = 0; mi < 4; mi++){
#pragma unroll
    for (int ni = 0; ni < 4; ni++){
      long gn = colBase + wn + ni * 16 + (lane & 15);
      float bb = 0.f;
      if (MODE == MODE_Q || MODE == MODE_V || MODE == MODE_OUT) bb = bias[gn];
      if (MODE == MODE_V){
        // f32 updated_v + fused bf16 transpose (vT[b,h,hd,kv])
        long gmBase = rowBase + wm + mi * 16 + ((lane >> 4) << 2);
        long b = gmBase >> 12, kv = gmBase & 4095;
        long h = gn >> 6, hd = gn & 63;
        long fidx = ((b * SH + h) * SKV + kv) * SHD + hd;
        ushort4 pk;
        float v0 = acc[mi][ni][0] + bb; outF[fidx          ] = v0; pk.x = f2bf(v0);
        float v1 = acc[mi][ni][1] + bb; outF[fidx +     SHD] = v1; pk.y = f2bf(v1);
        float v2 = acc[mi][ni][2] + bb; outF[fidx + 2 * SHD] = v2; pk.z = f2bf(v2);
        float v3 = acc[mi][ni][3] + bb; outF[fidx + 3 * SHD] = v3; pk.w = f2bf(v3);
        *reinterpret_cast<ushort4*>(outB + ((b * SH + h) * SHD + hd) * SKV + kv) = pk;
      } else {
#pragma unroll
        for (int r = 0; r < 4; r++){
          long gm = rowBase + wm + mi * 16 + ((lane >> 4) << 2) + r;
          float val = acc[mi][ni][r] + bb;
          if (MODE == MODE_OUT){
            outF[gm * 1024 + gn] = val;
          } else if (MODE == MODE_Q){
            long b = gm >> 9, s = gm & 511;
            long h = gn >> 6, hd = gn & 63;
            outB[((b * SH + h) * SS + s) * SHD + hd] = f2bf(val);
          } else { // MODE_K
            long b = gm >> 12, kv = gm & 4095;
            long h = gn >> 6, hd = gn & 63;
            long idx = ((b * SH + h) * SKV + kv) * SHD + hd;
            outF[idx] = val;
            outB[idx] = f2bf(val);
          }
        }
      }
    }
  }
}

// ---------- flash attention partial, swapped-operand + LDS-staged K/V ----------
// Per wave: 16 q rows. Lane c=lane&15 owns q-row c; hi=lane>>4.
// S^T[kv][q]: sT[ni][r] = S[kv=16ni+4hi+r][q=c]  -> softmax per-lane scalar m/l
// O^T[hd][q]: acc[ni][r] = O[hd=16ni+4hi+r][q=c]
// K tile (64 kv x 64 hd) and V^T tile (64 hd x 64 kv) staged in LDS once per
// block, shared by 4 waves -> 4x global-traffic cut. XOR swizzle (row&7)<<4.
__global__ __launch_bounds__(256) void attn_partial(const u16* __restrict__ qb,
                                                    const u16* __restrict__ kb,
                                                    const u16* __restrict__ vTb,
                                                    float* __restrict__ opart,
                                                    float* __restrict__ ml){
  __shared__ u16 Klds[64 * 64];             // [kv][hd], 128B rows, swizzled
  __shared__ u16 Vlds[64 * 64];             // [hd][kv], 128B rows, swizzled
  __shared__ u16 PT[4][16 * 72];            // per-wave P^T[q][kv], stride 72 u16
  const int tid  = threadIdx.x;
  const int lane = tid & 63;
  const int wid  = tid >> 6;
  const int c    = lane & 15;
  const int hi   = lane >> 4;
  const long bh  = blockIdx.x;
  const int  qt  = blockIdx.y;
  const int  split = blockIdx.z;

  // Q as B-fragment: lane holds Q[q=c][hd = hi*8 .. +8] (+32 for k-half 1)
  const u16* qp = qb + (bh * SS + qt * 64 + wid * 16 + c) * SHD + hi * 8;
  const bf16x8 bq0 = ld_frag_g(qp);
  const bf16x8 bq1 = ld_frag_g(qp + 32);

  f32x4 acc[4];
#pragma unroll
  for (int i = 0; i < 4; i++) acc[i] = (f32x4){0.f, 0.f, 0.f, 0.f};
  float mrun = -INFINITY, lrun = 0.f;

  const u16* kbase = kb  + bh * SKV * SHD;
  const u16* vbase = vTb + bh * SHD * SKV;
  u16* pt = &PT[wid][0];
  char* kch = reinterpret_cast<char*>(Klds);
  char* vch = reinterpret_cast<char*>(Vlds);

  for (int kt = split * 16; kt < split * 16 + 16; ++kt){
    __syncthreads();                        // previous tile's readers done
#pragma unroll
    for (int i = 0; i < 2; i++){
      int u = tid + i * 256;                // [0,512): 64 rows x 8 x 16B
      int r = u >> 3, cc = u & 7;
      uint4 kv4 = *reinterpret_cast<const uint4*>(kbase + (kt * 64 + r) * SHD + cc * 8);
      uint4 vv4 = *reinterpret_cast<const uint4*>(vbase + (long)r * SKV + kt * 64 + cc * 8);
      int ob = (r * 128 + cc * 16) ^ ((r & 7) << 4);
      *reinterpret_cast<uint4*>(kch + ob) = kv4;
      *reinterpret_cast<uint4*>(vch + ob) = vv4;
    }
    __syncthreads();

    // S^T = K · Q^T : 8 MFMAs, K-frags from LDS
    f32x4 sT[4];
#pragma unroll
    for (int ni = 0; ni < 4; ni++){
      int krow = ni * 16 + c;
      int swz = (krow & 7) << 4;
      int a0 = (krow * 128 + hi * 16) ^ swz;
      int a1 = (krow * 128 + 64 + hi * 16) ^ swz;
      f32x4 z = (f32x4){0.f, 0.f, 0.f, 0.f};
      sT[ni] = __builtin_amdgcn_mfma_f32_16x16x32_bf16(ld_frag_lds(kch, a0), bq0, z, 0, 0, 0);
      sT[ni] = __builtin_amdgcn_mfma_f32_16x16x32_bf16(ld_frag_lds(kch, a1), bq1, sT[ni], 0, 0, 0);
      sT[ni] *= 0.125f;                     // 1/sqrt(64)
    }
    // per-lane softmax for q-row c
    f32x4 mv = __builtin_elementwise_max(__builtin_elementwise_max(sT[0], sT[1]),
                                         __builtin_elementwise_max(sT[2], sT[3]));
    float t = fmaxf(fmaxf(mv[0], mv[1]), fmaxf(mv[2], mv[3]));
    t = fmaxf(t, __shfl_xor(t, 16));
    t = fmaxf(t, __shfl_xor(t, 32));
    float mn = fmaxf(mrun, t);
    float al = __expf(mrun - mn);
    f32x4 psv = (f32x4){0.f, 0.f, 0.f, 0.f};
#pragma unroll
    for (int ni = 0; ni < 4; ni++){
      f32x4 p;
      p[0] = __expf(sT[ni][0] - mn); p[1] = __expf(sT[ni][1] - mn);
      p[2] = __expf(sT[ni][2] - mn); p[3] = __expf(sT[ni][3] - mn);
      psv += p;
      ushort4 pk;
      pk.x = f2bf(p[0]); pk.y = f2bf(p[1]); pk.z = f2bf(p[2]); pk.w = f2bf(p[3]);
      *reinterpret_cast<ushort4*>(pt + c * 72 + ni * 16 + hi * 4) = pk;
    }
    float ps = (psv[0] + psv[1]) + (psv[2] + psv[3]);
    ps += __shfl_xor(ps, 16);
    ps += __shfl_xor(ps, 32);
    lrun = lrun * al + ps;
    mrun = mn;
#pragma unroll
    for (int ni = 0; ni < 4; ni++) acc[ni] *= al;
    // O^T += V^T · P^T : 8 MFMAs, V-frags from LDS
#pragma unroll
    for (int m = 0; m < 2; m++){
      bf16x8 pfrag = __builtin_bit_cast(bf16x8,
          *reinterpret_cast<const uint4*>(pt + c * 72 + m * 32 + hi * 8));
#pragma unroll
      for (int ni = 0; ni < 4; ni++){
        int vrow = ni * 16 + c;
        int av = (vrow * 128 + m * 64 + hi * 16) ^ ((vrow & 7) << 4);
        acc[ni] = __builtin_amdgcn_mfma_f32_16x16x32_bf16(ld_frag_lds(vch, av), pfrag, acc[ni], 0, 0, 0);
      }
    }
  }

  // epilogue: unnormalized O^T partials + per-row m,l
  const long row = bh * SS + (long)qt * 64 + wid * 16 + c;
  float* ob = opart + ((long)split * NROWS + row) * SHD;
#pragma unroll
  for (int ni = 0; ni < 4; ni++)
    *reinterpret_cast<f32x4*>(ob + ni * 16 + hi * 4) = acc[ni];
  if (hi == 0){
    ml[(long)split * NROWS + row] = mrun;
    ml[(long)NSPLIT * NROWS + (long)split * NROWS + row] = lrun;
  }
}

// ---------- combine partials -> attnb bf16 [B,S,D] ----------
__global__ __launch_bounds__(256) void attn_combine(const float* __restrict__ opart,
                                                    const float* __restrict__ ml,
                                                    u16* __restrict__ attnb){
  long idx4 = (long)blockIdx.x * 256 + threadIdx.x;   // float4 id, 16 per row
  long row = idx4 >> 4;
  int  c   = (int)(idx4 & 15);
  float m0 = ml[row], m1 = ml[NROWS + row], m2 = ml[2L*NROWS + row], m3 = ml[3L*NROWS + row];
  float M = fmaxf(fmaxf(m0, m1), fmaxf(m2, m3));
  float w0 = __expf(m0 - M), w1 = __expf(m1 - M), w2 = __expf(m2 - M), w3 = __expf(m3 - M);
  const float* lb = ml + (long)NSPLIT * NROWS;
  float L = w0*lb[row] + w1*lb[NROWS+row] + w2*lb[2L*NROWS+row] + w3*lb[3L*NROWS+row];
  float inv = 1.f / L;
  const float4* op = reinterpret_cast<const float4*>(opart);
  float4 v0 = op[(0L*NROWS + row) * 16 + c];
  float4 v1 = op[(1L*NROWS + row) * 16 + c];
  float4 v2 = op[(2L*NROWS + row) * 16 + c];
  float4 v3 = op[(3L*NROWS + row) * 16 + c];
  float4 val;
  val.x = (w0*v0.x + w1*v1.x + w2*v2.x + w3*v3.x) * inv;
  val.y = (w0*v0.y + w1*v1.y + w2*v2.y + w3*v3.y) * inv;
  val.z = (w0*v0.z + w1*v1.z + w2*v2.z + w3*v3.z) * inv;
  val.w = (w0*v0.w + w1*v1.w + w2*v2.w + w3*v3.w) * inv;
  long bh = row >> 9, s = row & 511;
  long b = bh >> 4, h = bh & 15;
  ushort4 u;
  u.x = f2bf(val.x); u.y = f2bf(val.y); u.z = f2bf(val.z); u.w = f2bf(val.w);
  reinterpret_cast<ushort4*>(attnb)[((b * SS + s) * SD + h * SHD) / 4 + c] = u;
}

extern "C" void kernel_launch(void* const* d_in, const int* in_sizes, int n_in,
                              void* d_out, int out_size, void* d_ws, size_t ws_size,
                              hipStream_t stream)
{
  const float* x  = (const float*)d_in[0];
  const float* xa = (const float*)d_in[1];
  const float* Wq = (const float*)d_in[2];
  const float* bq = (const float*)d_in[3];
  const float* Wk = (const float*)d_in[4];
  const float* Wv = (const float*)d_in[5];
  const float* bv = (const float*)d_in[6];
  const float* Wo = (const float*)d_in[7];
  const float* bo = (const float*)d_in[8];

  float* outO = (float*)d_out;
  float* outK = outO + (long)SB * SS * SD;
  float* outV = outK + (long)SB * SH * SKV * SHD;

  u16* ws   = (u16*)d_ws;
  u16* xb   = ws;                                     // 2M u16 (reused as attnb)
  u16* xab  = xb   + 2097152L;                        // 16.7M u16 (reused as opart f32)
  u16* Wqb  = xab  + 16777216L;
  u16* Wkb  = Wqb  + 1048576L;
  u16* Wvb  = Wkb  + 1048576L;
  u16* Wob  = Wvb  + 1048576L;
  u16* qbuf = Wob  + 1048576L;                        // [B,H,S,HD] bf16
  u16* kbuf = qbuf + 2097152L;                        // [B,H,KV,HD] bf16
  u16* vTbuf= kbuf + 16777216L;                       // [B,H,HD,KV] bf16
  u16* mlb  = vTbuf+ 16777216L;                       // 8*32768 f32

  u16*   attnb = xb;                                  // alias: xb dead after gemm_Q
  float* opart = (float*)xab;                         // alias: xab dead after gemm_V
  float* ml    = (float*)mlb;

  auto cast_launch = [&](const float* s, u16* d, long n){
    int n4 = (int)(n / 4);
    cast_kernel<<<(n4 + 255) / 256, 256, 0, stream>>>(s, d, n4);
  };
  cast_launch(x,  xb,  2097152L);
  cast_launch(xa, xab, 16777216L);
  cast_launch(Wq, Wqb, 1048576L);
  cast_launch(Wk, Wkb, 1048576L);
  cast_launch(Wv, Wvb, 1048576L);
  cast_launch(Wo, Wob, 1048576L);

  gemm_bt<MODE_Q>  <<<dim3(16, 8),  256, 0, stream>>>(xb,  Wqb, bq, nullptr, qbuf);
  gemm_bt<MODE_K>  <<<dim3(128, 8), 256, 0, stream>>>(xab, Wkb, nullptr, outK, kbuf);
  gemm_bt<MODE_V>  <<<dim3(128, 8), 256, 0, stream>>>(xab, Wvb, bv, outV, vTbuf);
  attn_partial     <<<dim3(64, 8, NSPLIT), 256, 0, stream>>>(qbuf, kbuf, vTbuf, opart, ml);
  attn_combine     <<<2048, 256, 0, stream>>>(opart, ml, attnb);
  gemm_bt<MODE_OUT><<<dim3(16, 8),  256, 0, stream>>>(attnb, Wob, bo, outO, nullptr);
}